// Round 1
// baseline (1133.108 us; speedup 1.0000x reference)
//
#include <hip/hip_runtime.h>
#include <cmath>

// Problem constants (B=16, T=2048, D=1024 per reference setup_inputs)
constexpr int BATCH  = 16;
constexpr int T      = 2048;
constexpr int D      = 1024;
constexpr int NTOK   = BATCH * T;        // 32768 tokens
constexpr int NUM_MASK = 1433;           // int(2048 * 0.7)
constexpr int ETILES = 16;               // D / TN

#define TM 64
#define TN 64
#define TKK 16

// K1: partial[token][etile] = sum_{e in tile} tanh(x[token]·W1[e] + b1[e]) * w2[e]
// fp32 VALU GEMM, 64x64 tile, K-step 16, deterministic e-order reduction.
__global__ __launch_bounds__(256) void k_scores_partial(
    const float* __restrict__ x, const float* __restrict__ W1,
    const float* __restrict__ b1, const float* __restrict__ w2,
    float* __restrict__ partial)
{
  __shared__ __align__(16) float As[TKK][TM + 4];
  __shared__ __align__(16) float Bs[TKK][TN + 4];
  __shared__ float red[TM][17];

  const int et = blockIdx.x;              // e-tile 0..15
  const int m0 = blockIdx.y * TM;         // token base
  const int n0 = et * TN;                 // e base
  const int t  = threadIdx.x;
  const int tx = t & 15;                  // token group
  const int ty = t >> 4;                  // e group
  const int lr = t >> 2;                  // load row 0..63
  const int lc = (t & 3) << 2;            // load k-offset 0,4,8,12

  float acc[4][4] = {};
  const float* aptr = x  + (size_t)(m0 + lr) * D + lc;
  const float* bptr = W1 + (size_t)(n0 + lr) * D + lc;

  for (int k0 = 0; k0 < D; k0 += TKK) {
    const float4 a4 = *(const float4*)(aptr + k0);
    const float4 b4 = *(const float4*)(bptr + k0);
    __syncthreads();
    As[lc + 0][lr] = a4.x; As[lc + 1][lr] = a4.y;
    As[lc + 2][lr] = a4.z; As[lc + 3][lr] = a4.w;
    Bs[lc + 0][lr] = b4.x; Bs[lc + 1][lr] = b4.y;
    Bs[lc + 2][lr] = b4.z; Bs[lc + 3][lr] = b4.w;
    __syncthreads();
#pragma unroll
    for (int kk = 0; kk < TKK; ++kk) {
      const float4 av = *(const float4*)&As[kk][tx << 2];
      const float4 bv = *(const float4*)&Bs[kk][ty << 2];
      const float a[4] = {av.x, av.y, av.z, av.w};
      const float b[4] = {bv.x, bv.y, bv.z, bv.w};
#pragma unroll
      for (int i = 0; i < 4; ++i)
#pragma unroll
        for (int j = 0; j < 4; ++j)
          acc[i][j] = fmaf(a[i], b[j], acc[i][j]);
    }
  }

  // epilogue: tanh, weight by w2, reduce over this block's 64 e's in ascending e order
  float p[4];
#pragma unroll
  for (int i = 0; i < 4; ++i) {
    float s = 0.f;
#pragma unroll
    for (int j = 0; j < 4; ++j) {
      const int n = n0 + (ty << 2) + j;
      s += tanhf(acc[i][j] + b1[n]) * w2[n];
    }
    p[i] = s;
  }
  __syncthreads();
#pragma unroll
  for (int i = 0; i < 4; ++i) red[(tx << 2) + i][ty] = p[i];
  __syncthreads();
  if (t < TM) {
    float s = 0.f;
#pragma unroll
    for (int j = 0; j < 16; ++j) s += red[t][j];   // ty ascending => e ascending
    partial[(size_t)(m0 + t) * ETILES + et] = s;
  }
}

// K2a: per batch — s = sum(partial) + b2 (deterministic e order), softmax -> w_buf
__global__ __launch_bounds__(256) void k_softmax(
    const float* __restrict__ partial, const float* __restrict__ b2,
    float* __restrict__ s_buf, float* __restrict__ w_buf)
{
  const int b = blockIdx.x;
  const int t = threadIdx.x;
  __shared__ __align__(16) float s[T];
  __shared__ float red[8];

  const float b2v = b2[0];
  for (int i = t; i < T; i += 256) {
    const float* p = partial + (size_t)(b * T + i) * ETILES;
    float a = 0.f;
#pragma unroll
    for (int j = 0; j < ETILES; ++j) a += p[j];
    const float v = a + b2v;
    s[i] = v;
    s_buf[b * T + i] = v;
  }
  __syncthreads();

  float m = -INFINITY;
  for (int i = t; i < T; i += 256) m = fmaxf(m, s[i]);
  for (int off = 32; off > 0; off >>= 1) m = fmaxf(m, __shfl_down(m, off));
  if ((t & 63) == 0) red[t >> 6] = m;
  __syncthreads();
  if (t == 0) {
    float mm = -INFINITY;
    for (int i = 0; i < 4; ++i) mm = fmaxf(mm, red[i]);
    red[4] = mm;
  }
  __syncthreads();
  m = red[4];
  __syncthreads();

  float zs = 0.f;
  for (int i = t; i < T; i += 256) zs += expf(s[i] - m);
  for (int off = 32; off > 0; off >>= 1) zs += __shfl_down(zs, off);
  if ((t & 63) == 0) red[t >> 6] = zs;
  __syncthreads();
  if (t == 0) {
    float zz = 0.f;
    for (int i = 0; i < 4; ++i) zz += red[i];
    red[5] = zz;
  }
  __syncthreads();
  const float Z = red[5];

  for (int i = t; i < T; i += 256) w_buf[b * T + i] = expf(s[i] - m) / Z;
}

// K2b: exact stable rank (rank_i = #{s_j<s_i} + #{s_j==s_i && j<i}); mask rank<1433.
// grid (T/256, BATCH): 128 blocks, 1 token/thread, O(T) count vs LDS copy.
__global__ __launch_bounds__(256) void k_mask(
    const float* __restrict__ s_buf, const float* __restrict__ w_buf,
    float* __restrict__ mw, float* __restrict__ out_w)
{
  const int b  = blockIdx.y;
  const int i0 = blockIdx.x * 256;
  const int t  = threadIdx.x;
  __shared__ __align__(16) float s[T];
  for (int i = t; i < T; i += 256) s[i] = s_buf[b * T + i];
  __syncthreads();

  const int i = i0 + t;
  const float si = s[i];
  int r = 0;
  const float4* s4 = (const float4*)s;
#pragma unroll 4
  for (int j4 = 0; j4 < T / 4; ++j4) {
    const float4 v = s4[j4];
    const int jb = j4 * 4;
    r += (v.x < si) || ((v.x == si) && (jb + 0 < i));
    r += (v.y < si) || ((v.y == si) && (jb + 1 < i));
    r += (v.z < si) || ((v.z == si) && (jb + 2 < i));
    r += (v.w < si) || ((v.w == si) && (jb + 3 < i));
  }
  const float v = (r < NUM_MASK) ? 0.f : w_buf[b * T + i];
  mw[b * T + i]    = v;
  out_w[b * T + i] = v;
}

// K3: out[b,t,d] = x[b,t,d] * mw[b,t], float4 grid-stride
__global__ __launch_bounds__(256) void k_output(
    const float4* __restrict__ x4, const float* __restrict__ mw,
    float4* __restrict__ out4)
{
  const int n4 = NTOK * (D / 4);  // 8388608
  int idx = blockIdx.x * blockDim.x + threadIdx.x;
  const int stride = gridDim.x * blockDim.x;
  for (; idx < n4; idx += stride) {
    float4 v = x4[idx];
    const float wv = mw[idx >> 8];  // 256 float4 per token
    v.x *= wv; v.y *= wv; v.z *= wv; v.w *= wv;
    out4[idx] = v;
  }
}

extern "C" void kernel_launch(void* const* d_in, const int* in_sizes, int n_in,
                              void* d_out, int out_size, void* d_ws, size_t ws_size,
                              hipStream_t stream) {
  const float* x  = (const float*)d_in[0];
  const float* W1 = (const float*)d_in[1];
  const float* b1 = (const float*)d_in[2];
  const float* w2 = (const float*)d_in[3];
  const float* b2 = (const float*)d_in[4];
  float* out = (float*)d_out;

  // workspace layout (all fully rewritten every launch; poison-safe)
  float* partial = (float*)d_ws;                          // NTOK*16 = 2 MB
  float* s_buf   = partial + (size_t)NTOK * ETILES;       // 128 KB
  float* w_buf   = s_buf + NTOK;                          // 128 KB
  float* mw      = w_buf + NTOK;                          // 128 KB

  dim3 g1(ETILES, NTOK / TM);   // (16, 512)
  hipLaunchKernelGGL(k_scores_partial, g1, dim3(256), 0, stream, x, W1, b1, w2, partial);
  hipLaunchKernelGGL(k_softmax, dim3(BATCH), dim3(256), 0, stream, partial, b2, s_buf, w_buf);
  hipLaunchKernelGGL(k_mask, dim3(T / 256, BATCH), dim3(256), 0, stream,
                     s_buf, w_buf, mw, out + (size_t)NTOK * D);
  hipLaunchKernelGGL(k_output, dim3(8192), dim3(256), 0, stream,
                     (const float4*)x, mw, (float4*)out);
}

// Round 2
// 547.376 us; speedup vs baseline: 2.0701x; 2.0701x over previous
//
#include <hip/hip_runtime.h>
#include <cmath>

// Problem constants (B=16, T=2048, D=1024 per reference setup_inputs)
constexpr int BATCH  = 16;
constexpr int T      = 2048;
constexpr int D      = 1024;
constexpr int NTOK   = BATCH * T;        // 32768 tokens
constexpr int NUM_MASK = 1433;           // int(2048 * 0.7)
constexpr int PCOLS  = 8;                // partial columns = N tiles (1024/128)

typedef __attribute__((ext_vector_type(8))) short short8;
typedef __attribute__((ext_vector_type(4))) float f32x4;

static __device__ __forceinline__ unsigned short bf16_rne(float f) {
  unsigned int u = __float_as_uint(f);
  u += 0x7fffu + ((u >> 16) & 1u);
  return (unsigned short)(u >> 16);
}
static __device__ __forceinline__ float bf16_to_f(unsigned short h) {
  return __uint_as_float(((unsigned int)h) << 16);
}
// 2 floats -> packed hi-bf16 dword + packed lo-bf16 dword (residual split)
static __device__ __forceinline__ void cvt2(float a, float b,
                                            unsigned int& hi, unsigned int& lo) {
  unsigned short ha = bf16_rne(a), hb = bf16_rne(b);
  unsigned short la = bf16_rne(a - bf16_to_f(ha));
  unsigned short lb = bf16_rne(b - bf16_to_f(hb));
  hi = (unsigned int)ha | ((unsigned int)hb << 16);
  lo = (unsigned int)la | ((unsigned int)lb << 16);
}

// K0: split W1 (fp32, 1024x1024) into bf16 hi/lo planes once.
__global__ __launch_bounds__(256) void k_convW(
    const float4* __restrict__ W1, uint2* __restrict__ Wh, uint2* __restrict__ Wl)
{
  const int i = blockIdx.x * 256 + threadIdx.x;   // 262144 float4s
  const float4 v = W1[i];
  unsigned int h0, l0, h1, l1;
  cvt2(v.x, v.y, h0, l0);
  cvt2(v.z, v.w, h1, l1);
  Wh[i] = make_uint2(h0, h1);
  Wl[i] = make_uint2(l0, l1);
}

// K1: partial[token][ntile] = sum_{e in 128-tile} tanh(x·W1[e] + b1[e]) * w2[e]
// Split-bf16 MFMA GEMM: acc = x_hi·W_hi + x_lo·W_hi + x_hi·W_lo (fp32 acc).
// 128x128 block tile, BK=32, 4 waves (2x2 of 64x64), 16x16x32 bf16 MFMA.
#define LDA 40   // LDS row stride in shorts (80 B, 16B-aligned, even bank spread)
__global__ __launch_bounds__(256) void k_scores_mfma(
    const float* __restrict__ x, const unsigned short* __restrict__ Wh,
    const unsigned short* __restrict__ Wl, const float* __restrict__ b1,
    const float* __restrict__ w2, float* __restrict__ partial)
{
  __shared__ __align__(16) unsigned short Ah[128 * LDA];
  __shared__ __align__(16) unsigned short Al[128 * LDA];
  __shared__ __align__(16) unsigned short Bh[128 * LDA];
  __shared__ __align__(16) unsigned short Bl[128 * LDA];
  __shared__ float red[128][2];

  const int bx = blockIdx.x;            // n tile 0..7
  const int by = blockIdx.y;            // m tile 0..255
  const int n0 = bx * 128;
  const int m0 = by * 128;
  const int t    = threadIdx.x;
  const int lane = t & 63;
  const int w    = t >> 6;              // wave 0..3
  const int wm   = (w >> 1) * 64;
  const int wn   = (w & 1) * 64;
  const int c    = lane & 15;
  const int q    = lane >> 4;

  // staging role: row r (0..127), k-half h (16 elements each)
  const int r   = t >> 1;
  const int h16 = (t & 1) * 16;

  const float*          aptr  = x  + (size_t)(m0 + r) * D + h16;
  const unsigned short* bhptr = Wh + (size_t)(n0 + r) * D + h16;
  const unsigned short* blptr = Wl + (size_t)(n0 + r) * D + h16;

  f32x4 acc[4][4];
#pragma unroll
  for (int i = 0; i < 4; ++i)
#pragma unroll
    for (int j = 0; j < 4; ++j)
      acc[i][j] = (f32x4){0.f, 0.f, 0.f, 0.f};

  for (int k0 = 0; k0 < D; k0 += 32) {
    // global loads
    const float4 a0 = *(const float4*)(aptr + k0 + 0);
    const float4 a1 = *(const float4*)(aptr + k0 + 4);
    const float4 a2 = *(const float4*)(aptr + k0 + 8);
    const float4 a3 = *(const float4*)(aptr + k0 + 12);
    const uint4 bh0 = *(const uint4*)(bhptr + k0);
    const uint4 bh1 = *(const uint4*)(bhptr + k0 + 8);
    const uint4 bl0 = *(const uint4*)(blptr + k0);
    const uint4 bl1 = *(const uint4*)(blptr + k0 + 8);

    // convert A to hi/lo bf16
    uint4 hA0, lA0, hA1, lA1;
    cvt2(a0.x, a0.y, hA0.x, lA0.x); cvt2(a0.z, a0.w, hA0.y, lA0.y);
    cvt2(a1.x, a1.y, hA0.z, lA0.z); cvt2(a1.z, a1.w, hA0.w, lA0.w);
    cvt2(a2.x, a2.y, hA1.x, lA1.x); cvt2(a2.z, a2.w, hA1.y, lA1.y);
    cvt2(a3.x, a3.y, hA1.z, lA1.z); cvt2(a3.z, a3.w, hA1.w, lA1.w);

    __syncthreads();   // previous tile's MFMA reads done
    *(uint4*)&Ah[r * LDA + h16]     = hA0;
    *(uint4*)&Ah[r * LDA + h16 + 8] = hA1;
    *(uint4*)&Al[r * LDA + h16]     = lA0;
    *(uint4*)&Al[r * LDA + h16 + 8] = lA1;
    *(uint4*)&Bh[r * LDA + h16]     = bh0;
    *(uint4*)&Bh[r * LDA + h16 + 8] = bh1;
    *(uint4*)&Bl[r * LDA + h16]     = bl0;
    *(uint4*)&Bl[r * LDA + h16 + 8] = bl1;
    __syncthreads();

    // fragment loads: A[m=lane&15][k=q*8+j], row-major LDS [m][k]
    short8 avh[4], avl[4], bvh[4], bvl[4];
#pragma unroll
    for (int i = 0; i < 4; ++i) {
      const int ar = (wm + i * 16 + c) * LDA + q * 8;
      const int br = (wn + i * 16 + c) * LDA + q * 8;
      avh[i] = *(const short8*)&Ah[ar];
      avl[i] = *(const short8*)&Al[ar];
      bvh[i] = *(const short8*)&Bh[br];
      bvl[i] = *(const short8*)&Bl[br];
    }
#pragma unroll
    for (int i = 0; i < 4; ++i)
#pragma unroll
      for (int j = 0; j < 4; ++j)
        acc[i][j] = __builtin_amdgcn_mfma_f32_16x16x32_bf16(avh[i], bvh[j], acc[i][j], 0, 0, 0);
#pragma unroll
    for (int i = 0; i < 4; ++i)
#pragma unroll
      for (int j = 0; j < 4; ++j)
        acc[i][j] = __builtin_amdgcn_mfma_f32_16x16x32_bf16(avl[i], bvh[j], acc[i][j], 0, 0, 0);
#pragma unroll
    for (int i = 0; i < 4; ++i)
#pragma unroll
      for (int j = 0; j < 4; ++j)
        acc[i][j] = __builtin_amdgcn_mfma_f32_16x16x32_bf16(avh[i], bvl[j], acc[i][j], 0, 0, 0);
  }

  // epilogue: tanh, weight by w2, reduce over this block's 128 e's.
  // C/D layout: n = wn + j*16 + c ; m = wm + i*16 + q*4 + reg
  float b1v[4], w2v[4];
#pragma unroll
  for (int j = 0; j < 4; ++j) {
    const int n = n0 + wn + j * 16 + c;
    b1v[j] = b1[n];
    w2v[j] = w2[n];
  }
  float rs[4][4];
#pragma unroll
  for (int i = 0; i < 4; ++i)
#pragma unroll
    for (int rr = 0; rr < 4; ++rr) {
      float s = 0.f;
#pragma unroll
      for (int j = 0; j < 4; ++j) {
        const float z = acc[i][j][rr] + b1v[j];
        const float th = 1.f - 2.f / (__expf(2.f * z) + 1.f);   // tanh, fast-exp
        s += th * w2v[j];
      }
      rs[i][rr] = s;
    }
  // butterfly-sum across the 16 'c' lanes
#pragma unroll
  for (int off = 1; off < 16; off <<= 1)
#pragma unroll
    for (int i = 0; i < 4; ++i)
#pragma unroll
      for (int rr = 0; rr < 4; ++rr)
        rs[i][rr] += __shfl_xor(rs[i][rr], off);
  if (c == 0) {
#pragma unroll
    for (int i = 0; i < 4; ++i)
#pragma unroll
      for (int rr = 0; rr < 4; ++rr)
        red[wm + i * 16 + q * 4 + rr][w & 1] = rs[i][rr];
  }
  __syncthreads();
  if (t < 128)
    partial[(size_t)(m0 + t) * PCOLS + bx] = red[t][0] + red[t][1];
}

// K2a: per batch — s = sum(partial) + b2, softmax -> w_buf
__global__ __launch_bounds__(256) void k_softmax(
    const float* __restrict__ partial, const float* __restrict__ b2,
    float* __restrict__ s_buf, float* __restrict__ w_buf)
{
  const int b = blockIdx.x;
  const int t = threadIdx.x;
  __shared__ __align__(16) float s[T];
  __shared__ float red[8];

  const float b2v = b2[0];
  for (int i = t; i < T; i += 256) {
    const float* p = partial + (size_t)(b * T + i) * PCOLS;
    float a = 0.f;
#pragma unroll
    for (int j = 0; j < PCOLS; ++j) a += p[j];
    const float v = a + b2v;
    s[i] = v;
    s_buf[b * T + i] = v;
  }
  __syncthreads();

  float m = -INFINITY;
  for (int i = t; i < T; i += 256) m = fmaxf(m, s[i]);
  for (int off = 32; off > 0; off >>= 1) m = fmaxf(m, __shfl_down(m, off));
  if ((t & 63) == 0) red[t >> 6] = m;
  __syncthreads();
  if (t == 0) {
    float mm = -INFINITY;
    for (int i = 0; i < 4; ++i) mm = fmaxf(mm, red[i]);
    red[4] = mm;
  }
  __syncthreads();
  m = red[4];
  __syncthreads();

  float zs = 0.f;
  for (int i = t; i < T; i += 256) zs += expf(s[i] - m);
  for (int off = 32; off > 0; off >>= 1) zs += __shfl_down(zs, off);
  if ((t & 63) == 0) red[t >> 6] = zs;
  __syncthreads();
  if (t == 0) {
    float zz = 0.f;
    for (int i = 0; i < 4; ++i) zz += red[i];
    red[5] = zz;
  }
  __syncthreads();
  const float Z = red[5];

  for (int i = t; i < T; i += 256) w_buf[b * T + i] = expf(s[i] - m) / Z;
}

// K2b: exact stable rank; mask rank<NUM_MASK.
__global__ __launch_bounds__(256) void k_mask(
    const float* __restrict__ s_buf, const float* __restrict__ w_buf,
    float* __restrict__ mw, float* __restrict__ out_w)
{
  const int b  = blockIdx.y;
  const int i0 = blockIdx.x * 256;
  const int t  = threadIdx.x;
  __shared__ __align__(16) float s[T];
  for (int i = t; i < T; i += 256) s[i] = s_buf[b * T + i];
  __syncthreads();

  const int i = i0 + t;
  const float si = s[i];
  int r = 0;
  const float4* s4 = (const float4*)s;
#pragma unroll 4
  for (int j4 = 0; j4 < T / 4; ++j4) {
    const float4 v = s4[j4];
    const int jb = j4 * 4;
    r += (v.x < si) || ((v.x == si) && (jb + 0 < i));
    r += (v.y < si) || ((v.y == si) && (jb + 1 < i));
    r += (v.z < si) || ((v.z == si) && (jb + 2 < i));
    r += (v.w < si) || ((v.w == si) && (jb + 3 < i));
  }
  const float v = (r < NUM_MASK) ? 0.f : w_buf[b * T + i];
  mw[b * T + i]    = v;
  out_w[b * T + i] = v;
}

// K3: out[b,t,d] = x[b,t,d] * mw[b,t], float4 grid-stride
__global__ __launch_bounds__(256) void k_output(
    const float4* __restrict__ x4, const float* __restrict__ mw,
    float4* __restrict__ out4)
{
  const int n4 = NTOK * (D / 4);
  int idx = blockIdx.x * blockDim.x + threadIdx.x;
  const int stride = gridDim.x * blockDim.x;
  for (; idx < n4; idx += stride) {
    float4 v = x4[idx];
    const float wv = mw[idx >> 8];
    v.x *= wv; v.y *= wv; v.z *= wv; v.w *= wv;
    out4[idx] = v;
  }
}

extern "C" void kernel_launch(void* const* d_in, const int* in_sizes, int n_in,
                              void* d_out, int out_size, void* d_ws, size_t ws_size,
                              hipStream_t stream) {
  const float* x  = (const float*)d_in[0];
  const float* W1 = (const float*)d_in[1];
  const float* b1 = (const float*)d_in[2];
  const float* w2 = (const float*)d_in[3];
  const float* b2 = (const float*)d_in[4];
  float* out = (float*)d_out;

  // workspace layout (~5.4 MB, fully rewritten every launch)
  unsigned short* Wh = (unsigned short*)d_ws;             // 2 MB
  unsigned short* Wl = Wh + (size_t)D * D;                // 2 MB
  float* partial = (float*)(Wl + (size_t)D * D);          // NTOK*8*4 = 1 MB
  float* s_buf   = partial + (size_t)NTOK * PCOLS;        // 128 KB
  float* w_buf   = s_buf + NTOK;                          // 128 KB
  float* mw      = w_buf + NTOK;                          // 128 KB

  hipLaunchKernelGGL(k_convW, dim3((D * D / 4) / 256), dim3(256), 0, stream,
                     (const float4*)W1, (uint2*)Wh, (uint2*)Wl);
  hipLaunchKernelGGL(k_scores_mfma, dim3(8, NTOK / 128), dim3(256), 0, stream,
                     x, Wh, Wl, b1, w2, partial);
  hipLaunchKernelGGL(k_softmax, dim3(BATCH), dim3(256), 0, stream, partial, b2, s_buf, w_buf);
  hipLaunchKernelGGL(k_mask, dim3(T / 256, BATCH), dim3(256), 0, stream,
                     s_buf, w_buf, mw, out + (size_t)NTOK * D);
  hipLaunchKernelGGL(k_output, dim3(8192), dim3(256), 0, stream,
                     (const float4*)x, mw, (float4*)out);
}